// Round 2
// baseline (262.355 us; speedup 1.0000x reference)
//
#include <hip/hip_runtime.h>

#define NSAMP 4096
#define NITER 200

// ---------------------------------------------------------------------------
// Setup: inv_item = inv(A^T A + 2*DtD + 5*I) via Woodbury.
// B = 5I + 2*DtD is circulant tridiagonal (diag 9, off-diag -2, wrapped).
// Binv first row via DFT eigenvalues lam_m = 9 - 4 cos(2 pi m/64), computed
// with ONE double cos per lane + Chebyshev recurrence (R1 version did 64
// serial double cos per lane ~= 60-90us; this is ~2us).
// inv_item = Binv - P^T Sinv P,  P = A Binv (9x64), S = I9 + P A^T (9x9).
// ---------------------------------------------------------------------------
__global__ __launch_bounds__(256) void setup_woodbury(const float* __restrict__ A,
                                                      float* __restrict__ inv_out) {
  __shared__ double lamr[64];    // 1/lambda_m
  __shared__ float binv[64];     // first row of circulant Binv
  __shared__ float P[9][64];
  __shared__ float Q[9][64];
  __shared__ double S[9][9];
  __shared__ double Sinv[9][9];
  __shared__ double W[9][18];
  const int tid = threadIdx.x;
  const double TWO_PI = 6.283185307179586476925286766559;

  // 1. eigen reciprocals + Binv first row (Chebyshev recurrence, double)
  double cb = 0.0;
  if (tid < 64) {
    cb = cos(TWO_PI * (double)tid / 64.0);   // the only transcendental
    lamr[tid] = 1.0 / (9.0 - 4.0 * cb);
  }
  __syncthreads();
  if (tid < 64) {
    // binv[d] = (1/64) sum_m cos(2 pi m d / 64) / lam_m ; beta = 2 pi d/64
    // c_m = cos(m*beta): c_0=1, c_1=cb, c_m = 2 cb c_{m-1} - c_{m-2}
    double cm1 = 1.0, c0 = cb;
    double acc = lamr[0] + cb * lamr[1];
    for (int m = 2; m < 64; ++m) {
      double c = 2.0 * cb * c0 - cm1;
      cm1 = c0;
      c0 = c;
      acc += c * lamr[m];
    }
    binv[tid] = (float)(acc / 64.0);
  }
  __syncthreads();

  // 2. P[m][i] = sum_k A[m][k] * Binv[k][i],  Binv[k][i] = binv[(k-i) mod 64]
  for (int e = tid; e < 9 * 64; e += 256) {
    int m = e >> 6, i = e & 63;
    double acc = 0.0;
    for (int k = 0; k < 64; ++k)
      acc += (double)A[m * 64 + k] * (double)binv[(k - i) & 63];
    P[m][i] = (float)acc;
  }
  __syncthreads();

  // 3. S = I9 + P A^T
  if (tid < 81) {
    int m = tid / 9, n = tid % 9;
    double acc = (m == n) ? 1.0 : 0.0;
    for (int i = 0; i < 64; ++i)
      acc += (double)P[m][i] * (double)A[n * 64 + i];
    S[m][n] = acc;
  }
  __syncthreads();

  // 4. Sinv (9x9 SPD) — single-thread double Gauss-Jordan (~2us, fine)
  if (tid == 0) {
    for (int r = 0; r < 9; ++r)
      for (int c = 0; c < 9; ++c) {
        W[r][c] = S[r][c];
        W[r][c + 9] = (r == c) ? 1.0 : 0.0;
      }
    for (int k = 0; k < 9; ++k) {
      double ip = 1.0 / W[k][k];
      for (int c = 0; c < 18; ++c) W[k][c] *= ip;
      for (int r = 0; r < 9; ++r)
        if (r != k) {
          double f = W[r][k];
          for (int c = 0; c < 18; ++c) W[r][c] -= f * W[k][c];
        }
    }
    for (int r = 0; r < 9; ++r)
      for (int c = 0; c < 9; ++c) Sinv[r][c] = W[r][c + 9];
  }
  __syncthreads();

  // 5. Q = Sinv P  (9x64)
  for (int e = tid; e < 9 * 64; e += 256) {
    int m = e >> 6, j = e & 63;
    double acc = 0.0;
    for (int n = 0; n < 9; ++n) acc += Sinv[m][n] * (double)P[n][j];
    Q[m][j] = (float)acc;
  }
  __syncthreads();

  // 6. inv_item[i][j] = Binv[i][j] - sum_m P[m][i] * Q[m][j]
  for (int e = tid; e < 64 * 64; e += 256) {
    int i = e >> 6, j = e & 63;
    float acc = binv[(i - j) & 63];
    for (int m = 0; m < 9; ++m) acc = fmaf(-P[m][i], Q[m][j], acc);
    inv_out[e] = acc;
  }
}

// ---------------------------------------------------------------------------
// Main ADMM kernel: one wave per sample; lane k owns element k.
// inv_item row `lane` PINNED in 64 VGPRs via empty asm (R1: compiler sank the
// loads into the loop, VGPR=44, ~2x instruction bloat).
// rbuf is strictly per-wave -> no __syncthreads needed: DS ops from one wave
// are processed in wave order; compiler orders the aliasing write/read and
// emits the lgkmcnt wait. wave_barrier() = free scheduling fence.
// ---------------------------------------------------------------------------
__global__ __launch_bounds__(256, 4) void admm_kernel(
    const float* __restrict__ target, const float* __restrict__ A,
    const float* __restrict__ x0, const float* __restrict__ invmat,
    float* __restrict__ out) {
  __shared__ float rbuf[4][64];
  const int tid = threadIdx.x;
  const int wid = tid >> 6;
  const int lane = tid & 63;
  const int s = blockIdx.x * 4 + wid;

  // --- ATb = (target_s @ A^T) @ A, via 9 wave-reductions ---
  float t = target[s * 64 + lane];
  float atb = 0.f;
#pragma unroll
  for (int m = 0; m < 9; ++m) {
    float a = A[m * 64 + lane];
    float p = t * a;
#pragma unroll
    for (int off = 32; off; off >>= 1) p += __shfl_xor(p, off, 64);
    atb = fmaf(a, p, atb);  // p = dot(target_s, A_m) in every lane
  }

  // --- load inv_item row `lane` into registers and PIN it there ---
  float inv_r[64];
  const float4* ir = reinterpret_cast<const float4*>(invmat + lane * 64);
#pragma unroll
  for (int q = 0; q < 16; ++q) {
    float4 v = ir[q];
    inv_r[4 * q + 0] = v.x;
    inv_r[4 * q + 1] = v.y;
    inv_r[4 * q + 2] = v.z;
    inv_r[4 * q + 3] = v.w;
  }
#pragma unroll
  for (int q = 0; q < 64; ++q) asm volatile("" : "+v"(inv_r[q]));

  float x = x0[s * 64 + lane];
  float eta = 0.f, tau = 0.f;
  const int nxt = (lane + 1) & 63;

  // Dx = D(x) carried across iterations (end-of-iter D(x_new) == next D(x))
  float xs = __shfl(x, nxt, 64);
  float Dx = xs - x;

  for (int it = 0; it < NITER; ++it) {
    // u_tv = soft_thresh(D(x) + eta/2, 5e-5)
    float v = fmaf(eta, 0.5f, Dx);
    float u = copysignf(fmaxf(fabsf(v) - 5e-5f, 0.f), v);
    // w = max(x + tau/5, 0)
    float w = fmaxf(fmaf(tau, 0.2f, x), 0.f);
    // resid = atb + D(2u - eta) + 5w - tau
    float tv = fmaf(2.f, u, -eta);
    float ts = __shfl(tv, nxt, 64);
    float resid = fmaf(5.f, w, atb) + (ts - tv) - tau;

    rbuf[wid][lane] = resid;
    __builtin_amdgcn_wave_barrier();

    // x = inv_item @ resid (broadcast LDS reads, conflict-free; 2 acc chains)
    float acc0 = 0.f, acc1 = 0.f;
#pragma unroll
    for (int j4 = 0; j4 < 16; j4 += 2) {
      float4 ra = *reinterpret_cast<const float4*>(&rbuf[wid][j4 * 4]);
      float4 rb = *reinterpret_cast<const float4*>(&rbuf[wid][j4 * 4 + 4]);
      acc0 = fmaf(inv_r[4 * j4 + 0], ra.x, acc0);
      acc0 = fmaf(inv_r[4 * j4 + 1], ra.y, acc0);
      acc0 = fmaf(inv_r[4 * j4 + 2], ra.z, acc0);
      acc0 = fmaf(inv_r[4 * j4 + 3], ra.w, acc0);
      acc1 = fmaf(inv_r[4 * j4 + 4], rb.x, acc1);
      acc1 = fmaf(inv_r[4 * j4 + 5], rb.y, acc1);
      acc1 = fmaf(inv_r[4 * j4 + 6], rb.z, acc1);
      acc1 = fmaf(inv_r[4 * j4 + 7], rb.w, acc1);
    }
    __builtin_amdgcn_wave_barrier();
    float xn = acc0 + acc1;

    // eta += 2*(D(x_new) - u); tau += 5*(x_new - w); carry Dx
    float xs2 = __shfl(xn, nxt, 64);
    Dx = xs2 - xn;
    eta = fmaf(2.f, Dx - u, eta);
    tau = fmaf(5.f, xn - w, tau);
    x = xn;
  }

  out[s * 64 + lane] = x;
}

extern "C" void kernel_launch(void* const* d_in, const int* in_sizes, int n_in,
                              void* d_out, int out_size, void* d_ws, size_t ws_size,
                              hipStream_t stream) {
  const float* target = (const float*)d_in[0];  // (4096, 64)
  const float* A = (const float*)d_in[1];       // (9, 64)
  const float* x0 = (const float*)d_in[2];      // (4096, 64)
  float* out = (float*)d_out;                   // (4096, 64)
  float* inv_ws = (float*)d_ws;                 // 64*64 floats scratch

  setup_woodbury<<<1, 256, 0, stream>>>(A, inv_ws);
  admm_kernel<<<NSAMP / 4, 256, 0, stream>>>(target, A, x0, inv_ws, out);
}

// Round 3
// 211.521 us; speedup vs baseline: 1.2403x; 1.2403x over previous
//
#include <hip/hip_runtime.h>

#define NSAMP 4096
#define NITER 200

typedef float v2f __attribute__((ext_vector_type(2)));

// ---------------------------------------------------------------------------
// Setup: inv_item = inv(A^T A + 2*DtD + 5*I) via Woodbury.
// B = 5I + 2*DtD circulant tridiagonal; Binv first row from DFT eigenvalues
// (one cos per lane + Chebyshev recurrence). Rank-9 correction via 9x9 GJ,
// now PARALLEL (162 threads) instead of single-thread. All inner loops
// unrolled so LDS latency pipelines.
// ---------------------------------------------------------------------------
__global__ __launch_bounds__(256) void setup_woodbury(const float* __restrict__ A,
                                                      float* __restrict__ inv_out) {
  __shared__ double lamr[64];
  __shared__ float binv[64];
  __shared__ float P[9][64];
  __shared__ float Q[9][64];
  __shared__ double W[9][18];
  const int tid = threadIdx.x;
  const double TWO_PI = 6.283185307179586476925286766559;

  // 1. eigen reciprocals + Binv first row (Chebyshev, double)
  double cb = 0.0;
  if (tid < 64) {
    cb = cos(TWO_PI * (double)tid / 64.0);
    lamr[tid] = 1.0 / (9.0 - 4.0 * cb);
  }
  __syncthreads();
  if (tid < 64) {
    double cm1 = 1.0, c0 = cb;
    double acc = lamr[0] + cb * lamr[1];
#pragma unroll 16
    for (int m = 2; m < 64; ++m) {
      double c = 2.0 * cb * c0 - cm1;
      cm1 = c0;
      c0 = c;
      acc += c * lamr[m];
    }
    binv[tid] = (float)(acc / 64.0);
  }
  __syncthreads();

  // 2. P[m][i] = sum_k A[m][k] * binv[(k-i)&63]
  for (int e = tid; e < 9 * 64; e += 256) {
    int m = e >> 6, i = e & 63;
    double acc = 0.0;
#pragma unroll 16
    for (int k = 0; k < 64; ++k)
      acc += (double)A[m * 64 + k] * (double)binv[(k - i) & 63];
    P[m][i] = (float)acc;
  }
  __syncthreads();

  // 3. W[:, 0:9] = S = I9 + P A^T ; W[:, 9:18] = I9
  if (tid < 81) {
    int m = tid / 9, n = tid % 9;
    double acc = (m == n) ? 1.0 : 0.0;
#pragma unroll 16
    for (int i = 0; i < 64; ++i)
      acc += (double)P[m][i] * (double)A[n * 64 + i];
    W[m][n] = acc;
    W[m][n + 9] = (m == n) ? 1.0 : 0.0;
  }
  __syncthreads();

  // 4. parallel Gauss-Jordan on [S | I] (162 threads, no pivoting: S is SPD)
  {
    const int r9 = tid / 18, c9 = tid % 18;
    const bool act = (tid < 162);
    for (int k = 0; k < 9; ++k) {
      double pv = 1.0, f = 0.0, wkc = 0.0;
      if (act) {
        pv = W[k][k];
        f = W[r9][k];
        wkc = W[k][c9];
      }
      __syncthreads();
      if (act) {
        double nk = wkc / pv;
        W[r9][c9] = (r9 == k) ? nk : fma(-f, nk, W[r9][c9]);
      }
      __syncthreads();
    }
  }

  // 5. Q = Sinv P  (Sinv = W[:, 9:18])
  for (int e = tid; e < 9 * 64; e += 256) {
    int m = e >> 6, j = e & 63;
    double acc = 0.0;
#pragma unroll
    for (int n = 0; n < 9; ++n) acc += W[m][n + 9] * (double)P[n][j];
    Q[m][j] = (float)acc;
  }
  __syncthreads();

  // 6. inv_item[i][j] = Binv[i][j] - sum_m P[m][i] * Q[m][j]
  for (int e = tid; e < 64 * 64; e += 256) {
    int i = e >> 6, j = e & 63;
    float acc = binv[(i - j) & 63];
#pragma unroll
    for (int m = 0; m < 9; ++m) acc = fmaf(-P[m][i], Q[m][j], acc);
    inv_out[e] = acc;
  }
}

// ---------------------------------------------------------------------------
// Main ADMM kernel: one wave per sample; lane k owns element k.
// inv_item row `lane` lives in 32 pinned float2 pairs (64 VGPRs); matvec is
// 32 x v_pk_fma_f32 (VOP3P packed fp32) consuming LDS-broadcast resid.
// amdgpu_waves_per_eu(4,4): allocator target = 4 waves/EU = 128 VGPR budget
// (launch_bounds' min-waves arg alone left the target at 8 -> spills in R2).
// Grid = 1024 blocks x 4 waves = exactly 4 blocks/CU: fully resident.
// ---------------------------------------------------------------------------
__global__ __launch_bounds__(256) __attribute__((amdgpu_waves_per_eu(4, 4)))
void admm_kernel(const float* __restrict__ target, const float* __restrict__ A,
                 const float* __restrict__ x0, const float* __restrict__ invmat,
                 float* __restrict__ out) {
  __shared__ __align__(16) float rbuf[4][64];
  const int tid = threadIdx.x;
  const int wid = tid >> 6;
  const int lane = tid & 63;
  const int s = blockIdx.x * 4 + wid;

  // --- ATb = (target_s @ A^T) @ A via 9 wave-reductions (one-time) ---
  float t = target[s * 64 + lane];
  float atb = 0.f;
#pragma unroll
  for (int m = 0; m < 9; ++m) {
    float a = A[m * 64 + lane];
    float p = t * a;
#pragma unroll
    for (int off = 32; off; off >>= 1) p += __shfl_xor(p, off, 64);
    atb = fmaf(a, p, atb);
  }

  // --- inv row `lane` into 32 pinned float2 pairs ---
  const float* mrow = invmat + lane * 64;
#define LOADM(i) v2f m##i = *reinterpret_cast<const v2f*>(mrow + 2 * (i)); \
                 asm("" : "+v"(m##i))
  LOADM(0);  LOADM(1);  LOADM(2);  LOADM(3);  LOADM(4);  LOADM(5);
  LOADM(6);  LOADM(7);  LOADM(8);  LOADM(9);  LOADM(10); LOADM(11);
  LOADM(12); LOADM(13); LOADM(14); LOADM(15); LOADM(16); LOADM(17);
  LOADM(18); LOADM(19); LOADM(20); LOADM(21); LOADM(22); LOADM(23);
  LOADM(24); LOADM(25); LOADM(26); LOADM(27); LOADM(28); LOADM(29);
  LOADM(30); LOADM(31);
#undef LOADM

  float* rb = &rbuf[wid][0];
  float x = x0[s * 64 + lane];
  float eta = 0.f, tau = 0.f;
  const int nxt = (lane + 1) & 63;
  float Dx = __shfl(x, nxt, 64) - x;

#pragma unroll 1
  for (int it = 0; it < NITER; ++it) {
    // u = soft_thresh(Dx + eta/2, 5e-5); w = relu(x + tau/5)
    float v = fmaf(eta, 0.5f, Dx);
    float u = copysignf(fmaxf(fabsf(v) - 5e-5f, 0.f), v);
    float w = fmaxf(fmaf(tau, 0.2f, x), 0.f);
    // resid = atb + D(2u - eta) + 5w - tau
    float tv = fmaf(2.f, u, -eta);
    float ts = __shfl(tv, nxt, 64);
    float resid = fmaf(5.f, w, atb) + (ts - tv) - tau;

    rb[lane] = resid;
    __builtin_amdgcn_wave_barrier();

    // x = inv_row . resid : 32 packed-fp32 FMAs, 4 independent chains
    v2f a0 = {0.f, 0.f}, a1 = {0.f, 0.f}, a2 = {0.f, 0.f}, a3 = {0.f, 0.f};
#define STEP2(j, accA, accB, mA, mB)                                        \
    {                                                                       \
      float4 r4 = *reinterpret_cast<const float4*>(rb + 4 * (j));           \
      v2f rlo = {r4.x, r4.y};                                               \
      v2f rhi = {r4.z, r4.w};                                               \
      asm("v_pk_fma_f32 %0, %1, %2, %0" : "+v"(accA) : "v"(mA), "v"(rlo));  \
      asm("v_pk_fma_f32 %0, %1, %2, %0" : "+v"(accB) : "v"(mB), "v"(rhi));  \
    }
    STEP2(0,  a0, a1, m0,  m1);
    STEP2(1,  a2, a3, m2,  m3);
    STEP2(2,  a0, a1, m4,  m5);
    STEP2(3,  a2, a3, m6,  m7);
    STEP2(4,  a0, a1, m8,  m9);
    STEP2(5,  a2, a3, m10, m11);
    STEP2(6,  a0, a1, m12, m13);
    STEP2(7,  a2, a3, m14, m15);
    STEP2(8,  a0, a1, m16, m17);
    STEP2(9,  a2, a3, m18, m19);
    STEP2(10, a0, a1, m20, m21);
    STEP2(11, a2, a3, m22, m23);
    STEP2(12, a0, a1, m24, m25);
    STEP2(13, a2, a3, m26, m27);
    STEP2(14, a0, a1, m28, m29);
    STEP2(15, a2, a3, m30, m31);
#undef STEP2
    __builtin_amdgcn_wave_barrier();
    float xn = ((a0.x + a0.y) + (a1.x + a1.y)) + ((a2.x + a2.y) + (a3.x + a3.y));

    // dual updates; carry Dx
    float xs2 = __shfl(xn, nxt, 64);
    Dx = xs2 - xn;
    eta = fmaf(2.f, Dx - u, eta);
    tau = fmaf(5.f, xn - w, tau);
    x = xn;
  }

  out[s * 64 + lane] = x;
}

extern "C" void kernel_launch(void* const* d_in, const int* in_sizes, int n_in,
                              void* d_out, int out_size, void* d_ws, size_t ws_size,
                              hipStream_t stream) {
  const float* target = (const float*)d_in[0];  // (4096, 64)
  const float* A = (const float*)d_in[1];       // (9, 64)
  const float* x0 = (const float*)d_in[2];      // (4096, 64)
  float* out = (float*)d_out;                   // (4096, 64)
  float* inv_ws = (float*)d_ws;                 // 64*64 floats scratch

  setup_woodbury<<<1, 256, 0, stream>>>(A, inv_ws);
  admm_kernel<<<NSAMP / 4, 256, 0, stream>>>(target, A, x0, inv_ws, out);
}